// Round 5
// baseline (431.035 us; speedup 1.0000x reference)
//
#include <hip/hip_runtime.h>
#include <hip/hip_cooperative_groups.h>
#include <math.h>

namespace cg = cooperative_groups;

#define NGRID 128
#define NG2 (NGRID * NGRID)
#define NG3 (NGRID * NGRID * NGRID)
#define CH 32
#define RAD 8
#define TPB 256
#define CBLOCKS 256   // cooperative grid: 1 block/CU guaranteed resident

constexpr float L_BOX = 10.0f;
constexpr float H = L_BOX / NGRID;   // 0.078125 — exact in fp32

__device__ __forceinline__ float silu(float v) {
    return v / (1.0f + expf(-v));
}

// Per-lane window: lane handles tap (px,py,pz); returns weight and flat index.
__device__ __forceinline__ void lane_tap(const float* __restrict__ pos, int i, int lane,
                                         float& w, int& addr) {
    int px = lane & 3, py = (lane >> 2) & 3, pz = (lane >> 4) & 3;
    float pwx = fmodf(pos[i * 3 + 0], L_BOX);
    float pwy = fmodf(pos[i * 3 + 1], L_BOX);
    float pwz = fmodf(pos[i * 3 + 2], L_BOX);
    int bx = (int)floorf(pwx / H);
    int by = (int)floorf(pwy / H);
    int bz = (int)floorf(pwz / H);
    int cx = bx + px - 1, cy = by + py - 1, cz = bz + pz - 1;
    float dx = (pwx - (float)cx * H) / H;
    float dy = (pwy - (float)cy * H) / H;
    float dz = (pwz - (float)cz * H) / H;
    w = expf(-0.5f * dx * dx) * expf(-0.5f * dy * dy) * expf(-0.5f * dz * dz);
    int ix = (cx + NGRID) & (NGRID - 1);
    int iy = (cy + NGRID) & (NGRID - 1);
    int iz = (cz + NGRID) & (NGRID - 1);
    addr = iz * NG2 + iy * NGRID + ix;
}

// ====================== fused cooperative kernel ======================
__global__ void __launch_bounds__(TPB, 2)
fused_all(const int* __restrict__ z, const float* __restrict__ pos,
          const float* __restrict__ emb,
          const float* __restrict__ W0, const float* __restrict__ b0,
          const float* __restrict__ W1, const float* __restrict__ b1,
          float* __restrict__ field, float* __restrict__ out, int N) {
    cg::grid_group grid = cg::this_grid();

    __shared__ float  tile[NGRID][32];   // 16 KB — conv phases
    __shared__ double sh[NGRID];         // 1 KB  — ker reduction
    __shared__ float  ker_sh[RAD + 1];

    int tid = threadIdx.x;
    int wave = tid >> 6, lane = tid & 63;
    int nb = gridDim.x;

    // ===== Phase A: zero field (grid-stride float4) + per-block ker table =====
    {
        float4* f4 = (float4*)field;
        const float4 z4 = make_float4(0.f, 0.f, 0.f, 0.f);
        for (int idx = blockIdx.x * TPB + tid; idx < NG3 / 4; idx += nb * TPB)
            f4[idx] = z4;

        // Exact periodic 1D kernel: inverse DFT of exp(-0.5*(2*pi*j'/NG)^2).
        double gauss = 0.0;
        if (tid < NGRID) {
            int jj = (tid < NGRID / 2) ? tid : tid - NGRID;
            double arg = (2.0 * M_PI * jj) / NGRID;   // sigma = h cancels
            gauss = exp(-0.5 * arg * arg);
        }
        for (int r = 0; r <= RAD; ++r) {
            if (tid < NGRID)
                sh[tid] = gauss * cos((2.0 * M_PI) * ((double)(tid * r) / NGRID));
            __syncthreads();
            for (int s = NGRID / 2; s >= 1; s >>= 1) {
                if (tid < s) sh[tid] += sh[tid + s];
                __syncthreads();
            }
            if (tid == 0) ker_sh[r] = (float)(sh[0] / NGRID);
            __syncthreads();
        }
    }
    __threadfence();
    grid.sync();   // field zeroed everywhere

    // ===== Phase B: scatter (wave per particle, grid-stride) =====
    for (int i = blockIdx.x * 4 + wave; i < N; i += nb * 4) {
        int sub = lane & 31;                 // channel (both half-waves identical)
        int zi = z[i];
        float x = emb[zi * CH + sub];

        float acc = b0[sub];
#pragma unroll
        for (int k = 0; k < CH; ++k)
            acc = fmaf(__shfl(x, k, 32), W0[sub * CH + k], acc);
        float h1 = silu(acc);

        acc = b1[sub];
#pragma unroll
        for (int k = 0; k < CH; ++k)
            acc = fmaf(__shfl(h1, k, 32), W1[sub * CH + k], acc);
        float s = silu(acc);
#pragma unroll
        for (int m = 16; m >= 1; m >>= 1) s += __shfl_xor(s, m, 32);

        float w; int addr;
        lane_tap(pos, i, lane, w, addr);
        atomicAdd(&field[addr], w * s);
    }
    __threadfence();
    grid.sync();

    float kk[RAD + 1];
#pragma unroll
    for (int r = 0; r <= RAD; ++r) kk[r] = ker_sh[r];

    // ===== Phase C: circular conv along x (task = pair of rows) =====
    {
        float* rows = &tile[0][0];
        int sub2 = tid >> 7;                 // which of 2 rows
        int t = tid & (NGRID - 1);
        for (int task = blockIdx.x; task < NG2 / 2; task += nb) {
            int base = (task * 2 + sub2) * NGRID;
            __syncthreads();
            rows[sub2 * NGRID + t] = field[base + t];
            __syncthreads();
            float acc = kk[0] * rows[sub2 * NGRID + t];
#pragma unroll
            for (int r = 1; r <= RAD; ++r)
                acc += kk[r] * (rows[sub2 * NGRID + ((t + r) & (NGRID - 1))] +
                                rows[sub2 * NGRID + ((t - r + NGRID) & (NGRID - 1))]);
            field[base + t] = acc;
        }
    }
    __threadfence();
    grid.sync();

    // ===== Phase D: circular conv along y (task = 128x32 tile) =====
    {
        int xl = tid & 31, c0 = tid >> 5;    // 0..7
        for (int task = blockIdx.x; task < NGRID * 4; task += nb) {
            int plane = task >> 2;           // z index
            int xt = task & 3;
            int base = plane * NG2 + xt * 32;
            __syncthreads();
            for (int c = c0; c < NGRID; c += 8)
                tile[c][xl] = field[base + c * NGRID + xl];
            __syncthreads();
            for (int c = c0; c < NGRID; c += 8) {
                float acc = kk[0] * tile[c][xl];
#pragma unroll
                for (int r = 1; r <= RAD; ++r)
                    acc += kk[r] * (tile[(c + r) & (NGRID - 1)][xl] +
                                    tile[(c - r + NGRID) & (NGRID - 1)][xl]);
                field[base + c * NGRID + xl] = acc;
            }
        }
    }
    __threadfence();
    grid.sync();

    // ===== Phase E: circular conv along z (task = 128x32 tile) =====
    {
        int xl = tid & 31, c0 = tid >> 5;
        for (int task = blockIdx.x; task < NGRID * 4; task += nb) {
            int plane = task >> 2;           // y index
            int xt = task & 3;
            int base = plane * NGRID + xt * 32;
            __syncthreads();
            for (int c = c0; c < NGRID; c += 8)
                tile[c][xl] = field[base + c * NG2 + xl];
            __syncthreads();
            for (int c = c0; c < NGRID; c += 8) {
                float acc = kk[0] * tile[c][xl];
#pragma unroll
                for (int r = 1; r <= RAD; ++r)
                    acc += kk[r] * (tile[(c + r) & (NGRID - 1)][xl] +
                                    tile[(c - r + NGRID) & (NGRID - 1)][xl]);
                field[base + c * NG2 + xl] = acc;
            }
        }
    }
    __threadfence();
    grid.sync();

    // ===== Phase F: gather (wave per particle, grid-stride) =====
    for (int i = blockIdx.x * 4 + wave; i < N; i += nb * 4) {
        float w; int addr;
        lane_tap(pos, i, lane, w, addr);
        float e = w * field[addr];
#pragma unroll
        for (int m = 32; m >= 1; m >>= 1) e += __shfl_xor(e, m, 64);
        if (lane == 0) out[i] = e;
    }
}

// ====================== fallback multi-kernel path (round-3-verified) ======================
__global__ void init_ker(float* ker) {
    __shared__ double sh[NGRID];
    int r = blockIdx.x;
    int j = threadIdx.x;
    int jj = (j < NGRID / 2) ? j : j - NGRID;
    double arg = (2.0 * M_PI * jj) / NGRID;
    sh[j] = exp(-0.5 * arg * arg) * cos((2.0 * M_PI) * ((double)(j * r) / NGRID));
    __syncthreads();
    for (int s = NGRID / 2; s >= 1; s >>= 1) {
        if (j < s) sh[j] += sh[j + s];
        __syncthreads();
    }
    if (j == 0) ker[r] = (float)(sh[0] / NGRID);
}

__global__ void scatter_wave(const int* __restrict__ z, const float* __restrict__ pos,
                             const float* __restrict__ emb,
                             const float* __restrict__ W0, const float* __restrict__ b0,
                             const float* __restrict__ W1, const float* __restrict__ b1,
                             float* __restrict__ field, int N) {
    int wave = threadIdx.x >> 6, lane = threadIdx.x & 63;
    int i = blockIdx.x * 4 + wave;
    if (i >= N) return;
    int sub = lane & 31;
    int zi = z[i];
    float x = emb[zi * CH + sub];
    float acc = b0[sub];
#pragma unroll
    for (int k = 0; k < CH; ++k) acc = fmaf(__shfl(x, k, 32), W0[sub * CH + k], acc);
    float h1 = silu(acc);
    acc = b1[sub];
#pragma unroll
    for (int k = 0; k < CH; ++k) acc = fmaf(__shfl(h1, k, 32), W1[sub * CH + k], acc);
    float s = silu(acc);
#pragma unroll
    for (int m = 16; m >= 1; m >>= 1) s += __shfl_xor(s, m, 32);
    float w; int addr;
    lane_tap(pos, i, lane, w, addr);
    atomicAdd(&field[addr], w * s);
}

__global__ void conv_x_k(float* __restrict__ field, const float* __restrict__ ker) {
    __shared__ float rows[2][NGRID];
    float k[RAD + 1];
#pragma unroll
    for (int r = 0; r <= RAD; ++r) k[r] = ker[r];
    int sub = threadIdx.x >> 7;
    int t = threadIdx.x & (NGRID - 1);
    int base = (blockIdx.x * 2 + sub) * NGRID;
    rows[sub][t] = field[base + t];
    __syncthreads();
    float acc = k[0] * rows[sub][t];
#pragma unroll
    for (int r = 1; r <= RAD; ++r)
        acc += k[r] * (rows[sub][(t + r) & (NGRID - 1)] +
                       rows[sub][(t - r + NGRID) & (NGRID - 1)]);
    field[base + t] = acc;
}

__global__ void conv_strided_k(float* __restrict__ field, const float* __restrict__ ker,
                               int s_conv, int s_fix) {
    __shared__ float tile[NGRID][32];
    float k[RAD + 1];
#pragma unroll
    for (int r = 0; r <= RAD; ++r) k[r] = ker[r];
    int x0 = blockIdx.x * 32;
    int base = blockIdx.y * s_fix + x0;
    int xl = threadIdx.x & 31;
    int c0 = threadIdx.x >> 5;
    for (int c = c0; c < NGRID; c += 8)
        tile[c][xl] = field[base + c * s_conv + xl];
    __syncthreads();
    for (int c = c0; c < NGRID; c += 8) {
        float acc = k[0] * tile[c][xl];
#pragma unroll
        for (int r = 1; r <= RAD; ++r)
            acc += k[r] * (tile[(c + r) & (NGRID - 1)][xl] +
                           tile[(c - r + NGRID) & (NGRID - 1)][xl]);
        field[base + c * s_conv + xl] = acc;
    }
}

__global__ void gather_wave(const float* __restrict__ pos,
                            const float* __restrict__ field,
                            float* __restrict__ out, int N) {
    int wave = threadIdx.x >> 6, lane = threadIdx.x & 63;
    int i = blockIdx.x * 4 + wave;
    if (i >= N) return;
    float w; int addr;
    lane_tap(pos, i, lane, w, addr);
    float e = w * field[addr];
#pragma unroll
    for (int m = 32; m >= 1; m >>= 1) e += __shfl_xor(e, m, 64);
    if (lane == 0) out[i] = e;
}

extern "C" void kernel_launch(void* const* d_in, const int* in_sizes, int n_in,
                              void* d_out, int out_size, void* d_ws, size_t ws_size,
                              hipStream_t stream) {
    const int*   z   = (const int*)d_in[0];
    const float* pos = (const float*)d_in[1];
    // d_in[2] = batch: all zeros with NBATCH=1 -> no effect on flat index.
    const float* emb = (const float*)d_in[3];
    const float* W0  = (const float*)d_in[4];
    const float* b0  = (const float*)d_in[5];
    const float* W1  = (const float*)d_in[6];
    const float* b1  = (const float*)d_in[7];
    int N = in_sizes[0];

    float* field = (float*)d_ws;          // NG^3 floats = 8 MB
    float* ker   = field + NG3;           // RAD+1 floats (fallback path only)
    float* outp  = (float*)d_out;

    void* args[] = {(void*)&z, (void*)&pos, (void*)&emb, (void*)&W0, (void*)&b0,
                    (void*)&W1, (void*)&b1, (void*)&field, (void*)&outp, (void*)&N};
    hipError_t e = hipLaunchCooperativeKernel((const void*)fused_all, dim3(CBLOCKS),
                                              dim3(TPB), args, 0, stream);
    if (e != hipSuccess) {
        // Verified round-3 multi-kernel fallback (same work every call).
        hipMemsetAsync(field, 0, NG3 * sizeof(float), stream);
        init_ker<<<RAD + 1, NGRID, 0, stream>>>(ker);
        scatter_wave<<<(N + 3) / 4, 256, 0, stream>>>(z, pos, emb, W0, b0, W1, b1, field, N);
        conv_x_k<<<NG2 / 2, 256, 0, stream>>>(field, ker);
        conv_strided_k<<<dim3(4, NGRID), 256, 0, stream>>>(field, ker, NGRID, NG2);
        conv_strided_k<<<dim3(4, NGRID), 256, 0, stream>>>(field, ker, NG2, NGRID);
        gather_wave<<<(N + 3) / 4, 256, 0, stream>>>(pos, field, outp, N);
    }
}